// Round 3
// baseline (833.542 us; speedup 1.0000x reference)
//
#include <hip/hip_runtime.h>

// LIF recurrence: T=512, B=64, N=4096. Pure HBM stream (1.07 GB total).
// R2 (resubmit; prior round was a broker timeout): latency-bound fix.
// float2/thread (2 waves/SIMD, 512 blocks) + explicit 16-deep load batching
// so 16 global_load_dwordx2 are in flight per wave (first consumer waits
// vmcnt(15), not vmcnt(0)). Plain loads/stores.

typedef float f32x2 __attribute__((ext_vector_type(2)));

namespace {
constexpr int kT   = 512;
constexpr int kB   = 64;
constexpr int kN   = 4096;
constexpr int kBN  = kB * kN;       // 262144 elements per timestep
constexpr int kBN2 = kBN / 2;       // 131072 float2 columns per timestep
constexpr int kU   = 16;            // timesteps per load batch (512 % 16 == 0)
constexpr float kDecay = 0.05f;     // DT/TAU = 1/20
constexpr float kEta   = 0.1f;
constexpr float kMinTh = 0.5f;
constexpr float kMaxTh = 2.0f;
}  // namespace

__global__ __launch_bounds__(256) void lif_kernel(const f32x2* __restrict__ in,
                                                  f32x2* __restrict__ out) {
  // Match XLA: no FMA contraction — spike threshold is bit-sensitive.
#pragma clang fp contract(off)
  const int col = blockIdx.x * blockDim.x + threadIdx.x;  // [0, kBN2)

  f32x2 V  = {0.0f, 0.0f};
  f32x2 Th = {1.0f, 1.0f};

  const f32x2* ip = in + col;
  f32x2* op = out + col;

  for (int g = 0; g < kT / kU; ++g) {
    // Phase 1: issue all kU loads (independent addresses -> kU loads in flight).
    f32x2 Ibuf[kU];
#pragma unroll
    for (int u = 0; u < kU; ++u) {
      Ibuf[u] = ip[u * kBN2];
    }

    // Phase 2: serial LIF recurrence on the registered inputs.
    f32x2 Sbuf[kU];
#pragma unroll
    for (int u = 0; u < kU; ++u) {
      const f32x2 I = Ibuf[u];
      f32x2 S;
#define LIF_STEP(c)                                              \
      {                                                          \
        float d = I.c - V.c;                                     \
        float p = kDecay * d;                                    \
        float v = V.c + p;                                       \
        float s = (v >= Th.c) ? 1.0f : 0.0f;                     \
        V.c = (v >= Th.c) ? 0.0f : v;                            \
        S.c = s;                                                 \
        Th.c = fminf(fmaxf(Th.c + kEta * s, kMinTh), kMaxTh);    \
      }
      LIF_STEP(x)
      LIF_STEP(y)
#undef LIF_STEP
      Sbuf[u] = S;
    }

    // Phase 3: stores (fire-and-forget; no wait on store completion).
#pragma unroll
    for (int u = 0; u < kU; ++u) {
      op[u * kBN2] = Sbuf[u];
    }

    ip += kU * kBN2;
    op += kU * kBN2;
  }
}

extern "C" void kernel_launch(void* const* d_in, const int* in_sizes, int n_in,
                              void* d_out, int out_size, void* d_ws, size_t ws_size,
                              hipStream_t stream) {
  const f32x2* in = reinterpret_cast<const f32x2*>(d_in[0]);
  f32x2* out = reinterpret_cast<f32x2*>(d_out);

  const int threads = 256;
  const int blocks = kBN2 / threads;  // 131072 / 256 = 512 blocks (2 per CU)
  lif_kernel<<<dim3(blocks), dim3(threads), 0, stream>>>(in, out);
}